// Round 2
// baseline (1163.987 us; speedup 1.0000x reference)
//
#include <hip/hip_runtime.h>
#include <cmath>

#define HDIM 2048
#define H4   (HDIM / 4)
#define NEXP 64
#define TTOT 16384
#define BM   64
#define BK   32
#define NITER (HDIM / BK)   // 64
#define LDB    (NEXP + 4)   // 68 floats: b128 reads stay 16B-aligned, 2-way alias (free)
#define LDS_SC 65           // odd stride: epilogue row reads conflict-free

// ---------------------------------------------------------------------------
// One block = 64 tokens x 64 experts, 1024 threads (16 waves = 4/SIMD).
// Intra-block split-K x4: kgroup = tid>>8 handles 8 of each 32-k tile.
// A (x) goes global->VGPR directly (16-lane same-address broadcast per wave);
// only B (gate_w tile, 8 KB/iter) is staged in LDS (double-buffered).
// fp32 FMA throughout (no fp32 MFMA on CDNA4); fused bias/top-2/softmax/aux.
// ---------------------------------------------------------------------------
__global__ __launch_bounds__(1024, 4) void router_main(
    const float* __restrict__ x,        // [T, H]
    const float* __restrict__ gw,       // [E, H]
    const float* __restrict__ rep,      // [E]
    const float* __restrict__ loads,    // [E]
    const float* __restrict__ counts,   // [E]
    const int*   __restrict__ total_dec,// [1]
    float* __restrict__ out_w,          // [T*2]
    float* __restrict__ out_idx,        // [T*2] (indices as float)
    float* __restrict__ prob_acc,       // [E] ws accum (pre-zeroed)
    float* __restrict__ gate_acc)       // [E] ws accum (pre-zeroed)
{
    __shared__ float b_s[2][BK][LDB];     // gate tile, transposed [k][expert]
    __shared__ float sc_s[BM][LDS_SC];    // final scores
    __shared__ float bias_s[NEXP];
    __shared__ float m_s[BM], z_s[BM];
    __shared__ int   i1_s[BM], i2_s[BM];

    const int tid = threadIdx.x;
    const int tx  = tid & 15;         // expert group: experts 4tx..4tx+3
    const int ty  = (tid >> 4) & 15;  // token group:  tokens 4ty..4ty+3
    const int kg  = tid >> 8;         // K-split group 0..3 (wave-uniform)
    const int t0  = blockIdx.x * BM;

    // per-expert bias (EMA load update is identity: 0.9*l + 0.1*l = l)
    if (tid < NEXP) {
        float L = logf((float)(*total_dec) + 1.0f);
        bias_s[tid] = 0.1f * rep[tid] - 0.1f * loads[tid]
                    + 0.1f * sqrtf(L / (counts[tid] + 1e-10f));
    }

    const float4* __restrict__ x4 = reinterpret_cast<const float4*>(x);
    const float4* __restrict__ g4 = reinterpret_cast<const float4*>(gw);

    // B-stager role: threads 512..1023 stage the 64x32 gate tile (1 float4 ea.)
    const bool is_b = (tid >= 512);
    const int  be   = (tid - 512) >> 3;  // expert row 0..63
    const int  bc4  = tid & 7;           // float4 col 0..7

    // A row bases for this thread's 4 tokens
    size_t arow[4];
    #pragma unroll
    for (int i = 0; i < 4; ++i)
        arow[i] = (size_t)(t0 + ty * 4 + i) * H4 + kg * 2;

    float acc[4][4] = {};
    float4 a_even[4][2], a_odd[4][2];

    // ---- prologue: B tile 0 -> LDS, A iter-0 fragment -> regs ----
    {
        float4 br;
        if (is_b) br = g4[(size_t)be * H4 + bc4];
        #pragma unroll
        for (int i = 0; i < 4; ++i)
            #pragma unroll
            for (int c = 0; c < 2; ++c)
                a_even[i][c] = x4[arow[i] + c];
        if (is_b) {
            const float brr[4] = {br.x, br.y, br.z, br.w};
            #pragma unroll
            for (int u = 0; u < 4; ++u)
                b_s[0][bc4 * 4 + u][be] = brr[u];
        }
    }
    __syncthreads();

    // one K-step: compute on (ACUR, buf BUFI), prefetch iter IT+1 into ANXT
    auto step = [&](int it, float4 (&acur)[4][2], float4 (&anxt)[4][2], int bufi) {
        const bool hn = (it + 1 < NITER);
        float4 bnx;
        if (hn) {
            const int col = (it + 1) * 8;
            if (is_b) bnx = g4[(size_t)be * H4 + col + bc4];
            #pragma unroll
            for (int i = 0; i < 4; ++i)
                #pragma unroll
                for (int c = 0; c < 2; ++c)
                    anxt[i][c] = x4[arow[i] + col + c];
        }
        #pragma unroll
        for (int c = 0; c < 2; ++c)
            #pragma unroll
            for (int u = 0; u < 4; ++u) {
                const int kk = kg * 8 + c * 4 + u;
                const float4 bfv = *reinterpret_cast<const float4*>(&b_s[bufi][kk][tx * 4]);
                const float bf[4] = {bfv.x, bfv.y, bfv.z, bfv.w};
                #pragma unroll
                for (int i = 0; i < 4; ++i) {
                    const float av = reinterpret_cast<const float*>(&acur[i][c])[u];
                    #pragma unroll
                    for (int j = 0; j < 4; ++j)
                        acc[i][j] = fmaf(av, bf[j], acc[i][j]);
                }
            }
        if (hn && is_b) {
            const float brr[4] = {bnx.x, bnx.y, bnx.z, bnx.w};
            #pragma unroll
            for (int u = 0; u < 4; ++u)
                b_s[bufi ^ 1][bc4 * 4 + u][be] = brr[u];
        }
        __syncthreads();
    };

    for (int it = 0; it < NITER; it += 2) {
        step(it,     a_even, a_odd,  0);
        step(it + 1, a_odd,  a_even, 1);
    }

    // ---- reduce the 4 K-split partials into sc_s (+bias on first) ----
    #pragma unroll
    for (int g = 0; g < 4; ++g) {
        if (kg == g) {
            #pragma unroll
            for (int i = 0; i < 4; ++i)
                #pragma unroll
                for (int j = 0; j < 4; ++j) {
                    float* p = &sc_s[ty * 4 + i][tx * 4 + j];
                    if (g == 0) *p = acc[i][j] + bias_s[tx * 4 + j];
                    else        *p += acc[i][j];
                }
        }
        __syncthreads();
    }

    // ---- pass 1: per-token top-2 (strict '>' keeps lowest index), softmax ----
    if (tid < BM) {
        const int t = tid;
        float m1 = -INFINITY, m2 = -INFINITY;
        int   i1 = 0, i2 = 0;
        for (int e = 0; e < NEXP; ++e) {
            const float s = sc_s[t][e];
            if (s > m1)      { m2 = m1; i2 = i1; m1 = s; i1 = e; }
            else if (s > m2) { m2 = s; i2 = e; }
        }
        float z = 0.0f;
        for (int e = 0; e < NEXP; ++e) z += expf(sc_s[t][e] - m1);

        const float e2  = expf(m2 - m1);
        const float inv = 1.0f / (1.0f + e2);
        const int   gt  = t0 + t;
        reinterpret_cast<float2*>(out_w)[gt]   = make_float2(inv, e2 * inv);
        reinterpret_cast<float2*>(out_idx)[gt] = make_float2((float)i1, (float)i2);
        m_s[t] = m1; z_s[t] = z; i1_s[t] = i1; i2_s[t] = i2;
    }
    __syncthreads();

    // ---- pass 2: per-expert partial sums for aux loss ----
    if (tid < NEXP) {
        const int e = tid;
        float ps = 0.0f, gs = 0.0f;
        for (int t = 0; t < BM; ++t) {
            ps += expf(sc_s[t][e] - m_s[t]) / z_s[t];
            gs += (float)((i1_s[t] == e) + (i2_s[t] == e));
        }
        atomicAdd(&prob_acc[e], ps);
        atomicAdd(&gate_acc[e], gs);
    }
}

// ---------------------------------------------------------------------------
// aux = E * sum_e (gate_sum[e]/T) * (prob_sum[e]/T)
// ---------------------------------------------------------------------------
__global__ void router_aux(const float* __restrict__ prob_acc,
                           const float* __restrict__ gate_acc,
                           float* __restrict__ out_aux)
{
    const float invT = 1.0f / (float)TTOT;
    const int e = threadIdx.x;  // 64 threads = 1 wave
    float v = (gate_acc[e] * invT) * (prob_acc[e] * invT);
    #pragma unroll
    for (int off = 32; off > 0; off >>= 1)
        v += __shfl_down(v, off);
    if (e == 0) out_aux[0] = v * (float)NEXP;
}

extern "C" void kernel_launch(void* const* d_in, const int* in_sizes, int n_in,
                              void* d_out, int out_size, void* d_ws, size_t ws_size,
                              hipStream_t stream)
{
    const float* x      = (const float*)d_in[0];
    const float* gw     = (const float*)d_in[1];
    const float* rep    = (const float*)d_in[2];
    const float* loads  = (const float*)d_in[3];
    const float* counts = (const float*)d_in[4];
    const int*   total  = (const int*)d_in[5];

    float* out     = (float*)d_out;
    float* out_w   = out;            // [16384*2] routing weights
    float* out_idx = out + 32768;    // [16384*2] expert indices as float
    float* out_aux = out + 65536;    // [1] aux loss

    float* prob_acc = (float*)d_ws;
    float* gate_acc = prob_acc + NEXP;

    hipMemsetAsync(d_ws, 0, 2 * NEXP * sizeof(float), stream);
    router_main<<<dim3(TTOT / BM), dim3(1024), 0, stream>>>(
        x, gw, rep, loads, counts, total, out_w, out_idx, prob_acc, gate_acc);
    router_aux<<<dim3(1), dim3(64), 0, stream>>>(prob_acc, gate_acc, out_aux);
}

// Round 3
// 245.951 us; speedup vs baseline: 4.7326x; 4.7326x over previous
//
#include <hip/hip_runtime.h>
#include <cmath>

#define HDIM 2048
#define H4   (HDIM / 4)     // 512 float4 per row
#define NEXP 64
#define TTOT 16384
#define BM   64
#define BK   32
#define NITER_FULL (HDIM / BK)  // 64
#define KSPLIT 4
#define NITER_K (NITER_FULL / KSPLIT)  // 16
#define LDA  (BM + 4)       // 68 floats
#define LDB  (NEXP + 4)
#define LDS_SC 65

// ws layout: [0..63] prob_acc, [64..127] gate_acc, [128..] partials
#define WS_PARTIAL_OFF 128
#define PARTIAL_FLOATS ((size_t)(TTOT / BM) * KSPLIT * BM * NEXP)  // 256*4*4096

// ===========================================================================
// Kernel 1 (split-K): one block = 64 tokens x 64 experts x K=512 slice.
// Round-1 proven structure: A+B staged in LDS (double-buffered), 4x4 fp32
// microtile, 512 FMA per K-tile per wave. LDS = 34.8 KB -> 4 blocks/CU
// = 4 waves/SIMD.
// ===========================================================================
__global__ __launch_bounds__(256, 4) void router_gemm_k(
    const float* __restrict__ x,        // [T, H]
    const float* __restrict__ gw,       // [E, H]
    float* __restrict__ partial)        // [256][4][64*64]
{
    __shared__ float a_s[2][BK][LDA];
    __shared__ float b_s[2][BK][LDB];

    const int tid = threadIdx.x;
    const int tx  = tid & 15;
    const int ty  = tid >> 4;
    const int r0  = tid >> 3;
    const int c4  = tid & 7;
    const int tb  = blockIdx.x;
    const int kg  = blockIdx.y;
    const int t0  = tb * BM;
    const int kb  = kg * (H4 / KSPLIT);   // float4 offset of this K-slice

    const float4* __restrict__ x4 = reinterpret_cast<const float4*>(x) + (size_t)t0 * H4 + kb;
    const float4* __restrict__ g4 = reinterpret_cast<const float4*>(gw) + kb;

    float acc[4][4] = {};

#define STORE_TILE(BUFI, A0, A1, B0, B1) do {                                  \
        float _t0[4] = {(A0).x, (A0).y, (A0).z, (A0).w};                       \
        float _t1[4] = {(A1).x, (A1).y, (A1).z, (A1).w};                       \
        float _t2[4] = {(B0).x, (B0).y, (B0).z, (B0).w};                       \
        float _t3[4] = {(B1).x, (B1).y, (B1).z, (B1).w};                       \
        _Pragma("unroll")                                                      \
        for (int u = 0; u < 4; ++u) {                                          \
            a_s[BUFI][c4 * 4 + u][r0]      = _t0[u];                           \
            a_s[BUFI][c4 * 4 + u][r0 + 32] = _t1[u];                           \
            b_s[BUFI][c4 * 4 + u][r0]      = _t2[u];                           \
            b_s[BUFI][c4 * 4 + u][r0 + 32] = _t3[u];                           \
        } } while (0)

    {
        float4 a0 = x4[(size_t)r0 * H4 + c4];
        float4 a1 = x4[(size_t)(r0 + 32) * H4 + c4];
        float4 b0 = g4[(size_t)r0 * H4 + c4];
        float4 b1 = g4[(size_t)(r0 + 32) * H4 + c4];
        STORE_TILE(0, a0, a1, b0, b1);
    }
    __syncthreads();

    int buf = 0;
    for (int it = 0; it < NITER_K; ++it) {
        float4 na0, na1, nb0, nb1;
        const bool has_next = (it + 1 < NITER_K);
        if (has_next) {
            const int k4 = (it + 1) * (BK / 4);
            na0 = x4[(size_t)r0 * H4 + k4 + c4];
            na1 = x4[(size_t)(r0 + 32) * H4 + k4 + c4];
            nb0 = g4[(size_t)r0 * H4 + k4 + c4];
            nb1 = g4[(size_t)(r0 + 32) * H4 + k4 + c4];
        }

        #pragma unroll
        for (int kk = 0; kk < BK; ++kk) {
            const float4 afv = *reinterpret_cast<const float4*>(&a_s[buf][kk][ty * 4]);
            const float4 bfv = *reinterpret_cast<const float4*>(&b_s[buf][kk][tx * 4]);
            const float af[4] = {afv.x, afv.y, afv.z, afv.w};
            const float bf[4] = {bfv.x, bfv.y, bfv.z, bfv.w};
            #pragma unroll
            for (int i = 0; i < 4; ++i)
                #pragma unroll
                for (int j = 0; j < 4; ++j)
                    acc[i][j] = fmaf(af[i], bf[j], acc[i][j]);
        }

        if (has_next) STORE_TILE(buf ^ 1, na0, na1, nb0, nb1);
        __syncthreads();
        buf ^= 1;
    }
#undef STORE_TILE

    // write 64x64 partial: float (token*64 + expert)
    float4* pout = reinterpret_cast<float4*>(partial + ((size_t)tb * KSPLIT + kg) * (BM * NEXP));
    #pragma unroll
    for (int i = 0; i < 4; ++i)
        pout[(ty * 4 + i) * (NEXP / 4) + tx] =
            make_float4(acc[i][0], acc[i][1], acc[i][2], acc[i][3]);
}

// ===========================================================================
// Kernel 2: sum the 4 K-split partials + bias, top-2 + softmax + aux partials.
// ===========================================================================
__global__ __launch_bounds__(256) void router_reduce(
    const float* __restrict__ partial,
    const float* __restrict__ rep,
    const float* __restrict__ loads,
    const float* __restrict__ counts,
    const int*   __restrict__ total_dec,
    float* __restrict__ out_w,
    float* __restrict__ out_idx,
    float* __restrict__ prob_acc,
    float* __restrict__ gate_acc)
{
    __shared__ float sc_s[BM][LDS_SC];
    __shared__ float bias_s[NEXP];
    __shared__ float m_s[BM], z_s[BM];
    __shared__ int   i1_s[BM], i2_s[BM];

    const int tid = threadIdx.x;
    const int tb  = blockIdx.x;
    const int t0  = tb * BM;

    if (tid < NEXP) {
        float L = logf((float)(*total_dec) + 1.0f);
        bias_s[tid] = 0.1f * rep[tid] - 0.1f * loads[tid]
                    + 0.1f * sqrtf(L / (counts[tid] + 1e-10f));
    }
    __syncthreads();

    const float* p = partial + (size_t)tb * KSPLIT * (BM * NEXP);
    #pragma unroll
    for (int o = 0; o < (BM * NEXP) / 256; ++o) {
        const int idx = o * 256 + tid;
        float s = p[idx] + p[BM * NEXP + idx] + p[2 * BM * NEXP + idx] + p[3 * BM * NEXP + idx];
        sc_s[idx >> 6][idx & 63] = s + bias_s[idx & 63];
    }
    __syncthreads();

    // pass 1: per-token top-2 (strict '>' keeps lowest index), softmax weights
    if (tid < BM) {
        const int t = tid;
        float m1 = -INFINITY, m2 = -INFINITY;
        int   i1 = 0, i2 = 0;
        for (int e = 0; e < NEXP; ++e) {
            const float s = sc_s[t][e];
            if (s > m1)      { m2 = m1; i2 = i1; m1 = s; i1 = e; }
            else if (s > m2) { m2 = s; i2 = e; }
        }
        float z = 0.0f;
        for (int e = 0; e < NEXP; ++e) z += expf(sc_s[t][e] - m1);

        const float e2  = expf(m2 - m1);
        const float inv = 1.0f / (1.0f + e2);
        const int   gt  = t0 + t;
        reinterpret_cast<float2*>(out_w)[gt]   = make_float2(inv, e2 * inv);
        reinterpret_cast<float2*>(out_idx)[gt] = make_float2((float)i1, (float)i2);
        m_s[t] = m1; z_s[t] = z; i1_s[t] = i1; i2_s[t] = i2;
    }
    __syncthreads();

    // pass 2: per-expert partial sums for aux loss
    if (tid < NEXP) {
        const int e = tid;
        float ps = 0.0f, gs = 0.0f;
        for (int t = 0; t < BM; ++t) {
            ps += expf(sc_s[t][e] - m_s[t]) / z_s[t];
            gs += (float)((i1_s[t] == e) + (i2_s[t] == e));
        }
        atomicAdd(&prob_acc[e], ps);
        atomicAdd(&gate_acc[e], gs);
    }
}

// ===========================================================================
// Fallback (round-1 proven): single fused kernel, used if ws too small.
// ===========================================================================
__global__ __launch_bounds__(256) void router_main(
    const float* __restrict__ x,
    const float* __restrict__ gw,
    const float* __restrict__ rep,
    const float* __restrict__ loads,
    const float* __restrict__ counts,
    const int*   __restrict__ total_dec,
    float* __restrict__ out_w,
    float* __restrict__ out_idx,
    float* __restrict__ prob_acc,
    float* __restrict__ gate_acc)
{
    __shared__ float a_s[2][BK][LDA];
    __shared__ float b_s[2][BK][LDB];
    __shared__ float sc_s[BM][LDS_SC];
    __shared__ float bias_s[NEXP];
    __shared__ float m_s[BM], z_s[BM];
    __shared__ int   i1_s[BM], i2_s[BM];

    const int tid = threadIdx.x;
    const int tx  = tid & 15;
    const int ty  = tid >> 4;
    const int r0  = tid >> 3;
    const int c4  = tid & 7;
    const int t0  = blockIdx.x * BM;

    if (tid < NEXP) {
        float L = logf((float)(*total_dec) + 1.0f);
        bias_s[tid] = 0.1f * rep[tid] - 0.1f * loads[tid]
                    + 0.1f * sqrtf(L / (counts[tid] + 1e-10f));
    }

    const float4* __restrict__ x4 = reinterpret_cast<const float4*>(x) + (size_t)t0 * H4;
    const float4* __restrict__ g4 = reinterpret_cast<const float4*>(gw);

    float acc[4][4] = {};

#define STORE_TILE(BUFI, A0, A1, B0, B1) do {                                  \
        float _t0[4] = {(A0).x, (A0).y, (A0).z, (A0).w};                       \
        float _t1[4] = {(A1).x, (A1).y, (A1).z, (A1).w};                       \
        float _t2[4] = {(B0).x, (B0).y, (B0).z, (B0).w};                       \
        float _t3[4] = {(B1).x, (B1).y, (B1).z, (B1).w};                       \
        _Pragma("unroll")                                                      \
        for (int u = 0; u < 4; ++u) {                                          \
            a_s[BUFI][c4 * 4 + u][r0]      = _t0[u];                           \
            a_s[BUFI][c4 * 4 + u][r0 + 32] = _t1[u];                           \
            b_s[BUFI][c4 * 4 + u][r0]      = _t2[u];                           \
            b_s[BUFI][c4 * 4 + u][r0 + 32] = _t3[u];                           \
        } } while (0)

    {
        float4 a0 = x4[(size_t)r0 * H4 + c4];
        float4 a1 = x4[(size_t)(r0 + 32) * H4 + c4];
        float4 b0 = g4[(size_t)r0 * H4 + c4];
        float4 b1 = g4[(size_t)(r0 + 32) * H4 + c4];
        STORE_TILE(0, a0, a1, b0, b1);
    }
    __syncthreads();

    int buf = 0;
    for (int it = 0; it < NITER_FULL; ++it) {
        float4 na0, na1, nb0, nb1;
        const bool has_next = (it + 1 < NITER_FULL);
        if (has_next) {
            const int k4 = (it + 1) * (BK / 4);
            na0 = x4[(size_t)r0 * H4 + k4 + c4];
            na1 = x4[(size_t)(r0 + 32) * H4 + k4 + c4];
            nb0 = g4[(size_t)r0 * H4 + k4 + c4];
            nb1 = g4[(size_t)(r0 + 32) * H4 + k4 + c4];
        }
        #pragma unroll
        for (int kk = 0; kk < BK; ++kk) {
            const float4 afv = *reinterpret_cast<const float4*>(&a_s[buf][kk][ty * 4]);
            const float4 bfv = *reinterpret_cast<const float4*>(&b_s[buf][kk][tx * 4]);
            const float af[4] = {afv.x, afv.y, afv.z, afv.w};
            const float bf[4] = {bfv.x, bfv.y, bfv.z, bfv.w};
            #pragma unroll
            for (int i = 0; i < 4; ++i)
                #pragma unroll
                for (int j = 0; j < 4; ++j)
                    acc[i][j] = fmaf(af[i], bf[j], acc[i][j]);
        }
        if (has_next) STORE_TILE(buf ^ 1, na0, na1, nb0, nb1);
        __syncthreads();
        buf ^= 1;
    }
#undef STORE_TILE

    #pragma unroll
    for (int i = 0; i < 4; ++i)
        #pragma unroll
        for (int j = 0; j < 4; ++j)
            sc_s[ty * 4 + i][tx * 4 + j] = acc[i][j] + bias_s[tx * 4 + j];
    __syncthreads();

    if (tid < BM) {
        const int t = tid;
        float m1 = -INFINITY, m2 = -INFINITY;
        int   i1 = 0, i2 = 0;
        for (int e = 0; e < NEXP; ++e) {
            const float s = sc_s[t][e];
            if (s > m1)      { m2 = m1; i2 = i1; m1 = s; i1 = e; }
            else if (s > m2) { m2 = s; i2 = e; }
        }
        float z = 0.0f;
        for (int e = 0; e < NEXP; ++e) z += expf(sc_s[t][e] - m1);
        const float e2  = expf(m2 - m1);
        const float inv = 1.0f / (1.0f + e2);
        const int   gt  = t0 + t;
        reinterpret_cast<float2*>(out_w)[gt]   = make_float2(inv, e2 * inv);
        reinterpret_cast<float2*>(out_idx)[gt] = make_float2((float)i1, (float)i2);
        m_s[t] = m1; z_s[t] = z; i1_s[t] = i1; i2_s[t] = i2;
    }
    __syncthreads();

    if (tid < NEXP) {
        const int e = tid;
        float ps = 0.0f, gs = 0.0f;
        for (int t = 0; t < BM; ++t) {
            ps += expf(sc_s[t][e] - m_s[t]) / z_s[t];
            gs += (float)((i1_s[t] == e) + (i2_s[t] == e));
        }
        atomicAdd(&prob_acc[e], ps);
        atomicAdd(&gate_acc[e], gs);
    }
}

__global__ void router_aux(const float* __restrict__ prob_acc,
                           const float* __restrict__ gate_acc,
                           float* __restrict__ out_aux)
{
    const float invT = 1.0f / (float)TTOT;
    const int e = threadIdx.x;
    float v = (gate_acc[e] * invT) * (prob_acc[e] * invT);
    #pragma unroll
    for (int off = 32; off > 0; off >>= 1)
        v += __shfl_down(v, off);
    if (e == 0) out_aux[0] = v * (float)NEXP;
}

extern "C" void kernel_launch(void* const* d_in, const int* in_sizes, int n_in,
                              void* d_out, int out_size, void* d_ws, size_t ws_size,
                              hipStream_t stream)
{
    const float* x      = (const float*)d_in[0];
    const float* gw     = (const float*)d_in[1];
    const float* rep    = (const float*)d_in[2];
    const float* loads  = (const float*)d_in[3];
    const float* counts = (const float*)d_in[4];
    const int*   total  = (const int*)d_in[5];

    float* out     = (float*)d_out;
    float* out_w   = out;            // [16384*2] routing weights
    float* out_idx = out + 32768;    // [16384*2] expert indices as float
    float* out_aux = out + 65536;    // [1] aux loss

    float* prob_acc = (float*)d_ws;
    float* gate_acc = prob_acc + NEXP;
    float* partial  = (float*)d_ws + WS_PARTIAL_OFF;

    const size_t ws_needed = (WS_PARTIAL_OFF + PARTIAL_FLOATS) * sizeof(float);

    hipMemsetAsync(d_ws, 0, WS_PARTIAL_OFF * sizeof(float), stream);

    if (ws_size >= ws_needed) {
        router_gemm_k<<<dim3(TTOT / BM, KSPLIT), dim3(256), 0, stream>>>(x, gw, partial);
        router_reduce<<<dim3(TTOT / BM), dim3(256), 0, stream>>>(
            partial, rep, loads, counts, total, out_w, out_idx, prob_acc, gate_acc);
    } else {
        router_main<<<dim3(TTOT / BM), dim3(256), 0, stream>>>(
            x, gw, rep, loads, counts, total, out_w, out_idx, prob_acc, gate_acc);
    }
    router_aux<<<dim3(1), dim3(64), 0, stream>>>(prob_acc, gate_acc, out_aux);
}